// Round 2
// baseline (836.331 us; speedup 1.0000x reference)
//
#include <hip/hip_runtime.h>
#include <cstddef>

// ---------------- constants / layout ----------------
// N=256, OBS=256, ACT=16, H=512, Z=128, G=256, IN=512, HID=256
// d_out (float) offsets, return order:
constexpr size_t O_HNEW   = 0;         // 256*512
constexpr size_t O_NLL    = 131072;    // 256
constexpr size_t O_KL     = 131328;    // 256
constexpr size_t O_LOGITS = 131584;    // 256*16
constexpr size_t O_VALUES = 135680;    // 256
constexpr size_t O_MUQ    = 135936;    // 256*128
constexpr size_t O_LVQ    = 168704;    // 256*128
constexpr size_t O_Z      = 201472;    // 256*128
constexpr size_t O_VGAT   = 234240;    // 256*256

// workspace offsets (floats)
constexpr size_t W_T1    = 0;          // 256*512
constexpr size_t W_T2    = 131072;     // 256*512
constexpr size_t W_T3    = 262144;     // 256*512
constexpr size_t W_PBUF  = 393216;     // 256*256
constexpr size_t W_QBUF  = 458752;     // 256*256
constexpr size_t W_XBUF  = 524288;     // 256*512
constexpr size_t W_GI    = 655360;     // 256*1536
constexpr size_t W_GH    = 1048576;    // 256*1536
constexpr size_t W_WH1   = 1441792;    // 256*256
constexpr size_t W_WH2   = 1507328;    // 256*256
constexpr size_t W_H1    = 1572864;    // 256*256
constexpr size_t W_ALPHA = 1638400;    // 256*256
constexpr size_t W_CN    = 1703936;    // 256
constexpr size_t W_A1    = 1704192;    // 256
constexpr size_t W_B1    = 1704448;    // 256
constexpr size_t W_A2    = 1704704;    // 256
constexpr size_t W_B2    = 1704960;    // 256
constexpr size_t W_HA    = 1705216;    // 256*256
constexpr size_t W_HC    = 1770752;    // 256*256

#define DI __device__ __forceinline__

DI float sigm(float x)    { return 1.f / (1.f + expf(-x)); }
DI float clamp10(float x) { return fminf(fmaxf(x, -10.f), 10.f); }

// ---------------- generic GEMM: C = act(A @ W^T + b) ----------------
// A row = [A1 row (K1) | A2 row (K2)], W is (N, K) row-major, M = 256.
// BM=BN=64, BK=16, 256 threads, 4x4 microtile.
template<int ACTMODE>   // 0 none, 1 relu
__global__ __launch_bounds__(256) void gemm_bt(
    const float* __restrict__ A1, int K1,
    const float* __restrict__ A2, int K2,
    const float* __restrict__ W, const float* __restrict__ bias,
    float* __restrict__ C, int Nn)
{
    const int K = K1 + K2;
    __shared__ __align__(16) float As[16][68];
    __shared__ __align__(16) float Ws[16][68];
    int tid = threadIdx.x;
    int tx = tid & 15, ty = tid >> 4;
    int n0 = blockIdx.x * 64, m0 = blockIdx.y * 64;
    int lk = tid & 15, lr = tid >> 4;
    float acc[4][4] = {};
    for (int k0 = 0; k0 < K; k0 += 16) {
        int kg = k0 + lk;
        #pragma unroll
        for (int p = 0; p < 4; ++p) {
            int r = lr + p * 16;
            float av;
            int row = m0 + r;
            if (kg < K1) av = A1[(size_t)row * K1 + kg];
            else         av = A2[(size_t)row * K2 + (kg - K1)];
            As[lk][r] = av;
            Ws[lk][r] = W[(size_t)(n0 + r) * K + kg];
        }
        __syncthreads();
        #pragma unroll
        for (int kk = 0; kk < 16; ++kk) {
            float4 a4 = *(const float4*)&As[kk][ty * 4];
            float4 b4 = *(const float4*)&Ws[kk][tx * 4];
            float a_[4] = {a4.x, a4.y, a4.z, a4.w};
            float b_[4] = {b4.x, b4.y, b4.z, b4.w};
            #pragma unroll
            for (int i = 0; i < 4; ++i)
                #pragma unroll
                for (int j = 0; j < 4; ++j)
                    acc[i][j] = fmaf(a_[i], b_[j], acc[i][j]);
        }
        __syncthreads();
    }
    #pragma unroll
    for (int i = 0; i < 4; ++i) {
        int row = m0 + ty * 4 + i;
        int col = n0 + tx * 4;
        float4 o;
        float* po = &o.x;
        #pragma unroll
        for (int j = 0; j < 4; ++j) {
            float v = acc[i][j] + (bias ? bias[col + j] : 0.f);
            if (ACTMODE == 1) v = fmaxf(v, 0.f);
            po[j] = v;
        }
        *(float4*)&C[(size_t)row * Nn + col] = o;
    }
}

// ---------------- GEMM NN: C = act(A @ B), B is (K, N) row-major ----------------
template<int ACTMODE>   // 0 none, 2 elu
__global__ __launch_bounds__(256) void gemm_nn(
    const float* __restrict__ A, const float* __restrict__ B,
    float* __restrict__ C, int Nn, int K)
{
    __shared__ __align__(16) float As[16][68];
    __shared__ __align__(16) float Bs[16][68];
    int tid = threadIdx.x;
    int tx = tid & 15, ty = tid >> 4;
    int n0 = blockIdx.x * 64, m0 = blockIdx.y * 64;
    int lk = tid & 15, lr = tid >> 4;
    int bc = tid & 63, bk0 = tid >> 6;
    float acc[4][4] = {};
    for (int k0 = 0; k0 < K; k0 += 16) {
        #pragma unroll
        for (int p = 0; p < 4; ++p) {
            int r = lr + p * 16;
            As[lk][r] = A[(size_t)(m0 + r) * K + k0 + lk];
            int kk = bk0 * 4 + p;
            Bs[kk][bc] = B[(size_t)(k0 + kk) * Nn + n0 + bc];
        }
        __syncthreads();
        #pragma unroll
        for (int kk = 0; kk < 16; ++kk) {
            float4 a4 = *(const float4*)&As[kk][ty * 4];
            float4 b4 = *(const float4*)&Bs[kk][tx * 4];
            float a_[4] = {a4.x, a4.y, a4.z, a4.w};
            float b_[4] = {b4.x, b4.y, b4.z, b4.w};
            #pragma unroll
            for (int i = 0; i < 4; ++i)
                #pragma unroll
                for (int j = 0; j < 4; ++j)
                    acc[i][j] = fmaf(a_[i], b_[j], acc[i][j]);
        }
        __syncthreads();
    }
    #pragma unroll
    for (int i = 0; i < 4; ++i) {
        int row = m0 + ty * 4 + i;
        int col = n0 + tx * 4;
        float4 o;
        float* po = &o.x;
        #pragma unroll
        for (int j = 0; j < 4; ++j) {
            float v = acc[i][j];
            if (ACTMODE == 2) v = v > 0.f ? v : expf(v) - 1.f;
            po[j] = v;
        }
        *(float4*)&C[(size_t)row * Nn + col] = o;
    }
}

// ---------------- VRNN post: mu_q/lv_q/z to out, kl rowwise ----------------
__global__ __launch_bounds__(128) void post_pq(
    const float* __restrict__ pbuf, const float* __restrict__ qbuf,
    const float* __restrict__ eps, float* __restrict__ out)
{
    int i = blockIdx.x, tid = threadIdx.x;   // tid = d in [0,128)
    float mu_p = pbuf[(size_t)i * 256 + tid];
    float lv_p = clamp10(pbuf[(size_t)i * 256 + 128 + tid]);
    float mu_q = qbuf[(size_t)i * 256 + tid];
    float lv_q = clamp10(qbuf[(size_t)i * 256 + 128 + tid]);
    float z = mu_q + eps[(size_t)i * 128 + tid] * expf(0.5f * lv_q);
    out[O_MUQ + (size_t)i * 128 + tid] = mu_q;
    out[O_LVQ + (size_t)i * 128 + tid] = lv_q;
    out[O_Z   + (size_t)i * 128 + tid] = z;
    float ivp = expf(-lv_p);
    float dm = mu_q - mu_p;
    float t = dm * dm * ivp + expf(lv_q) * ivp + (lv_p - lv_q) - 1.f;
    __shared__ float red[2];
    #pragma unroll
    for (int off = 32; off; off >>= 1) t += __shfl_down(t, off);
    if ((tid & 63) == 0) red[tid >> 6] = t;
    __syncthreads();
    if (tid == 0) out[O_KL + i] = 0.5f * (red[0] + red[1]);
}

// ---------------- nll rowwise ----------------
__global__ __launch_bounds__(256) void nll_k(
    const float* __restrict__ xbuf, const float* __restrict__ obs,
    float* __restrict__ out)
{
    int i = blockIdx.x, tid = threadIdx.x;   // tid = d in [0,256)
    float mu = xbuf[(size_t)i * 512 + tid];
    float lv = clamp10(xbuf[(size_t)i * 512 + 256 + tid]);
    float d = obs[(size_t)i * 256 + tid] - mu;
    float t = d * d * expf(-lv) + lv;
    __shared__ float red[4];
    #pragma unroll
    for (int off = 32; off; off >>= 1) t += __shfl_down(t, off);
    if ((tid & 63) == 0) red[tid >> 6] = t;
    __syncthreads();
    if (tid == 0) out[O_NLL + i] = 0.5f * (red[0] + red[1] + red[2] + red[3]);
}

// ---------------- GRU gates ----------------
__global__ __launch_bounds__(256) void gru_k(
    const float* __restrict__ gi, const float* __restrict__ gh,
    const float* __restrict__ h_prev, float* __restrict__ out)
{
    int idx = blockIdx.x * 256 + threadIdx.x;
    int i = idx >> 9, h = idx & 511;
    const float* gir = gi + (size_t)i * 1536;
    const float* ghr = gh + (size_t)i * 1536;
    float r = sigm(gir[h] + ghr[h]);
    float u = sigm(gir[512 + h] + ghr[512 + h]);
    float c = tanhf(gir[1024 + h] + r * ghr[1024 + h]);
    float hp = h_prev[(size_t)i * 512 + h];
    out[O_HNEW + (size_t)i * 512 + h] = (1.f - u) * c + u * hp;
}

// ---------------- coop + cn (closed-form pairwise-KL row means) ----------------
__global__ __launch_bounds__(256) void coop_cn_k(
    const float* __restrict__ out, const float* __restrict__ cw,
    const float* __restrict__ cb, float* __restrict__ cn)
{
    __shared__ float S1[128], S2[128];
    __shared__ float red[4];
    __shared__ float CS[2];
    int tid = threadIdx.x;
    const float* muq = out + O_MUQ;
    const float* lvq = out + O_LVQ;
    float cpart = 0.f, sspart = 0.f;
    if (tid < 128) {
        float s1 = 0.f, s2 = 0.f;
        for (int i = 0; i < 256; ++i) {
            float mu = muq[(size_t)i * 128 + tid];
            float lv = lvq[(size_t)i * 128 + tid];
            float iv = expf(-lv);
            s1 += iv; s2 += mu * iv;
            cpart += mu * mu * iv;
            sspart += lv;
        }
        S1[tid] = s1; S2[tid] = s2;
    }
    float v = cpart;
    #pragma unroll
    for (int off = 32; off; off >>= 1) v += __shfl_down(v, off);
    if ((tid & 63) == 0) red[tid >> 6] = v;
    __syncthreads();
    if (tid == 0) CS[0] = red[0] + red[1] + red[2] + red[3];
    __syncthreads();
    v = sspart;
    #pragma unroll
    for (int off = 32; off; off >>= 1) v += __shfl_down(v, off);
    if ((tid & 63) == 0) red[tid >> 6] = v;
    __syncthreads();
    if (tid == 0) CS[1] = red[0] + red[1] + red[2] + red[3];
    __syncthreads();
    float Cval = CS[0], SS = CS[1];
    int i = tid;
    const float* mur = muq + (size_t)i * 128;
    const float* lvr = lvq + (size_t)i * 128;
    float acc1 = 0.f, acc2 = 0.f, slv = 0.f;
    for (int d = 0; d < 128; ++d) {
        float mu = mur[d], lv = lvr[d];
        acc1 += (mu * mu + expf(lv)) * S1[d];
        acc2 += mu * S2[d];
        slv += lv;
    }
    float coop = 0.5f * (acc1 - 2.f * acc2 + Cval + SS - 256.f * slv - 256.f * 128.f) / 255.f;
    cn[i] = sigm(cw[0] * coop + cb[0]);
}

// ---------------- GAT a/b vectors ----------------
__global__ __launch_bounds__(256) void gat_ab_k(
    const float* __restrict__ Wh, const float* __restrict__ asrc,
    const float* __restrict__ adst, const float* __restrict__ cn,
    float* __restrict__ a, float* __restrict__ b)
{
    int i = threadIdx.x;
    const float4* wr = (const float4*)(Wh + (size_t)i * 256);
    const float4* s4 = (const float4*)asrc;
    const float4* d4 = (const float4*)adst;
    float sa = 0.f, sb = 0.f;
    for (int q = 0; q < 64; ++q) {
        float4 w = wr[q], s = s4[q], d = d4[q];
        sa += w.x * s.x + w.y * s.y + w.z * s.z + w.w * s.w;
        sb += w.x * d.x + w.y * d.y + w.z * d.z + w.w * d.w;
    }
    float c = cn[i];
    a[i] = sa + c;
    b[i] = sb + c;
}

// ---------------- GAT softmax rows: alpha = softmax_j(lrelu(a_i + b_j)) ----------------
__global__ __launch_bounds__(256) void gat_softmax_k(
    const float* __restrict__ a, const float* __restrict__ b,
    float* __restrict__ alpha)
{
    __shared__ float bsh[256];
    __shared__ float ash[16];
    int tid = threadIdx.x;
    int b0 = blockIdx.x * 16;
    bsh[tid] = b[tid];
    if (tid < 16) ash[tid] = a[b0 + tid];
    __syncthreads();
    int li = tid >> 4, jg = tid & 15;
    float ai = ash[li];
    float e[16];
    float m = -1e30f;
    #pragma unroll
    for (int q = 0; q < 16; ++q) {
        float s = ai + bsh[jg * 16 + q];
        s = s > 0.f ? s : 0.2f * s;
        e[q] = s;
        m = fmaxf(m, s);
    }
    #pragma unroll
    for (int msk = 1; msk < 16; msk <<= 1) m = fmaxf(m, __shfl_xor(m, msk, 16));
    float sum = 0.f;
    #pragma unroll
    for (int q = 0; q < 16; ++q) { e[q] = expf(e[q] - m); sum += e[q]; }
    #pragma unroll
    for (int msk = 1; msk < 16; msk <<= 1) sum += __shfl_xor(sum, msk, 16);
    float inv = 1.f / sum;
    int i = b0 + li;
    float4* dst = (float4*)(alpha + (size_t)i * 256 + jg * 16);
    dst[0] = make_float4(e[0] * inv, e[1] * inv, e[2] * inv, e[3] * inv);
    dst[1] = make_float4(e[4] * inv, e[5] * inv, e[6] * inv, e[7] * inv);
    dst[2] = make_float4(e[8] * inv, e[9] * inv, e[10] * inv, e[11] * inv);
    dst[3] = make_float4(e[12] * inv, e[13] * inv, e[14] * inv, e[15] * inv);
}

// ---------------- per-agent head hidden layers (BW-bound GEMV stream) ----------------
__global__ __launch_bounds__(256) void heads_hidden_k(
    const float* __restrict__ obs, const float* __restrict__ out,
    const float* __restrict__ Wa1, const float* __restrict__ ba1,
    const float* __restrict__ Wc1, const float* __restrict__ bc1,
    float* __restrict__ ha, float* __restrict__ hc)
{
    int bid = blockIdx.x;
    int n = bid >> 2;
    int which = (bid >> 1) & 1;
    int half = bid & 1;
    __shared__ __align__(16) float xin[512];
    int tid = threadIdx.x;
    xin[tid]       = obs[(size_t)n * 256 + tid];
    xin[256 + tid] = out[O_VGAT + (size_t)n * 256 + tid];
    __syncthreads();
    const float* Wb = (which ? Wc1 : Wa1) + (size_t)n * 131072;
    const float* bb = (which ? bc1 : ba1) + (size_t)n * 256;
    float* hb = (which ? hc : ha) + (size_t)n * 256;
    int wave = tid >> 6, lane = tid & 63;
    const float4* xin4 = (const float4*)xin;
    float4 x0 = xin4[lane * 2], x1 = xin4[lane * 2 + 1];
    for (int r = wave; r < 128; r += 4) {
        int row = half * 128 + r;
        const float4* wr = (const float4*)(Wb + (size_t)row * 512);
        float4 w0 = wr[lane * 2], w1 = wr[lane * 2 + 1];
        float v = w0.x * x0.x + w0.y * x0.y + w0.z * x0.z + w0.w * x0.w
                + w1.x * x1.x + w1.y * x1.y + w1.z * x1.z + w1.w * x1.w;
        #pragma unroll
        for (int off = 32; off; off >>= 1) v += __shfl_down(v, off);
        if (lane == 0) hb[row] = fmaxf(v + bb[row], 0.f);
    }
}

// ---------------- head output layers ----------------
__global__ __launch_bounds__(256) void heads_out_k(
    const float* __restrict__ ha, const float* __restrict__ hc,
    const float* __restrict__ Wa2, const float* __restrict__ ba2,
    const float* __restrict__ Wc2, const float* __restrict__ bc2,
    float* __restrict__ out)
{
    int n = blockIdx.x, tid = threadIdx.x;
    __shared__ __align__(16) float hA[256], hC[256];
    hA[tid] = ha[(size_t)n * 256 + tid];
    hC[tid] = hc[(size_t)n * 256 + tid];
    __syncthreads();
    int wave = tid >> 6, lane = tid & 63;
    const float4* h4 = (const float4*)hA;
    float4 hv = h4[lane];
    for (int o = wave; o < 16; o += 4) {
        const float4* w4 = (const float4*)(Wa2 + ((size_t)n * 16 + o) * 256);
        float4 wv = w4[lane];
        float v = wv.x * hv.x + wv.y * hv.y + wv.z * hv.z + wv.w * hv.w;
        #pragma unroll
        for (int off = 32; off; off >>= 1) v += __shfl_down(v, off);
        if (lane == 0) out[O_LOGITS + (size_t)n * 16 + o] = v + ba2[(size_t)n * 16 + o];
    }
    if (wave == 0) {
        const float4* w4 = (const float4*)(Wc2 + (size_t)n * 256);
        const float4* h4c = (const float4*)hC;
        float4 wv = w4[lane], hcv = h4c[lane];
        float v = wv.x * hcv.x + wv.y * hcv.y + wv.z * hcv.z + wv.w * hcv.w;
        #pragma unroll
        for (int off = 32; off; off >>= 1) v += __shfl_down(v, off);
        if (lane == 0) out[O_VALUES + n] = v + bc2[n];
    }
}

// ---------------- launch ----------------
extern "C" void kernel_launch(void* const* d_in, const int* in_sizes, int n_in,
                              void* d_out_v, int out_size, void* d_ws, size_t ws_size,
                              hipStream_t stream)
{
    const float* obs   = (const float*)d_in[0];
    const float* h_prev= (const float*)d_in[1];
    const float* eps   = (const float*)d_in[2];
    const float* Wp1 = (const float*)d_in[3];  const float* bp1 = (const float*)d_in[4];
    const float* Wp2 = (const float*)d_in[5];  const float* bp2 = (const float*)d_in[6];
    const float* We1 = (const float*)d_in[7];  const float* be1 = (const float*)d_in[8];
    const float* We2 = (const float*)d_in[9];  const float* be2 = (const float*)d_in[10];
    const float* Wd1 = (const float*)d_in[11]; const float* bd1 = (const float*)d_in[12];
    const float* Wd2 = (const float*)d_in[13]; const float* bd2 = (const float*)d_in[14];
    const float* Wih = (const float*)d_in[15]; const float* Whh = (const float*)d_in[16];
    const float* bih = (const float*)d_in[17]; const float* bhh = (const float*)d_in[18];
    const float* Wg1 = (const float*)d_in[19]; const float* as1 = (const float*)d_in[20];
    const float* ad1 = (const float*)d_in[21];
    const float* Wg2 = (const float*)d_in[22]; const float* as2 = (const float*)d_in[23];
    const float* ad2 = (const float*)d_in[24];
    const float* cw  = (const float*)d_in[25]; const float* cb  = (const float*)d_in[26];
    const float* Wa1 = (const float*)d_in[27]; const float* ba1 = (const float*)d_in[28];
    const float* Wa2 = (const float*)d_in[29]; const float* ba2 = (const float*)d_in[30];
    const float* Wc1 = (const float*)d_in[31]; const float* bc1 = (const float*)d_in[32];
    const float* Wc2 = (const float*)d_in[33]; const float* bc2 = (const float*)d_in[34];
    float* out = (float*)d_out_v;
    float* ws  = (float*)d_ws;
    dim3 blk(256);

    // VRNN prior: t1 = relu(h_prev @ Wp1^T + bp1); p = t1 @ Wp2^T + bp2
    gemm_bt<1><<<dim3(8, 4), blk, 0, stream>>>(h_prev, 512, nullptr, 0, Wp1, bp1, ws + W_T1, 512);
    gemm_bt<0><<<dim3(4, 4), blk, 0, stream>>>(ws + W_T1, 512, nullptr, 0, Wp2, bp2, ws + W_PBUF, 256);
    // encoder: t2 = relu([obs,h_prev] @ We1^T + be1); q = t2 @ We2^T + be2
    gemm_bt<1><<<dim3(8, 4), blk, 0, stream>>>(obs, 256, h_prev, 512, We1, be1, ws + W_T2, 512);
    gemm_bt<0><<<dim3(4, 4), blk, 0, stream>>>(ws + W_T2, 512, nullptr, 0, We2, be2, ws + W_QBUF, 256);
    // mu_q / lv_q / z / kl
    post_pq<<<dim3(256), dim3(128), 0, stream>>>(ws + W_PBUF, ws + W_QBUF, eps, out);
    // decoder: t3 = relu([z,h_prev] @ Wd1^T + bd1); x = t3 @ Wd2^T + bd2
    gemm_bt<1><<<dim3(8, 4), blk, 0, stream>>>(out + O_Z, 128, h_prev, 512, Wd1, bd1, ws + W_T3, 512);
    gemm_bt<0><<<dim3(8, 4), blk, 0, stream>>>(ws + W_T3, 512, nullptr, 0, Wd2, bd2, ws + W_XBUF, 512);
    nll_k<<<dim3(256), blk, 0, stream>>>(ws + W_XBUF, obs, out);
    // GRU
    gemm_bt<0><<<dim3(24, 4), blk, 0, stream>>>(obs, 256, out + O_Z, 128, Wih, bih, ws + W_GI, 1536);
    gemm_bt<0><<<dim3(24, 4), blk, 0, stream>>>(h_prev, 512, nullptr, 0, Whh, bhh, ws + W_GH, 1536);
    gru_k<<<dim3(512), blk, 0, stream>>>(ws + W_GI, ws + W_GH, h_prev, out);
    // coop -> cn
    coop_cn_k<<<dim3(1), blk, 0, stream>>>(out, cw, cb, ws + W_CN);
    // GAT stage 1
    gemm_bt<0><<<dim3(4, 4), blk, 0, stream>>>(out + O_HNEW, 512, nullptr, 0, Wg1, nullptr, ws + W_WH1, 256);
    gat_ab_k<<<dim3(1), blk, 0, stream>>>(ws + W_WH1, as1, ad1, ws + W_CN, ws + W_A1, ws + W_B1);
    gat_softmax_k<<<dim3(16), blk, 0, stream>>>(ws + W_A1, ws + W_B1, ws + W_ALPHA);
    gemm_nn<2><<<dim3(4, 4), blk, 0, stream>>>(ws + W_ALPHA, ws + W_WH1, ws + W_H1, 256, 256);
    // GAT stage 2
    gemm_bt<0><<<dim3(4, 4), blk, 0, stream>>>(ws + W_H1, 256, nullptr, 0, Wg2, nullptr, ws + W_WH2, 256);
    gat_ab_k<<<dim3(1), blk, 0, stream>>>(ws + W_WH2, as2, ad2, ws + W_CN, ws + W_A2, ws + W_B2);
    gat_softmax_k<<<dim3(16), blk, 0, stream>>>(ws + W_A2, ws + W_B2, ws + W_ALPHA);
    gemm_nn<2><<<dim3(4, 4), blk, 0, stream>>>(ws + W_ALPHA, ws + W_WH2, out + O_VGAT, 256, 256);
    // per-agent actor/critic heads
    heads_hidden_k<<<dim3(1024), blk, 0, stream>>>(obs, out, Wa1, ba1, Wc1, bc1, ws + W_HA, ws + W_HC);
    heads_out_k<<<dim3(256), blk, 0, stream>>>(ws + W_HA, ws + W_HC, Wa2, ba2, Wc2, bc2, out);
}

// Round 4
// 652.250 us; speedup vs baseline: 1.2822x; 1.2822x over previous
//
#include <hip/hip_runtime.h>
#include <cstddef>

// ---------------- constants / layout ----------------
// N=256, OBS=256, ACT=16, H=512, Z=128, G=256, IN=512, HID=256
// d_out (float) offsets, return order:
constexpr size_t O_HNEW   = 0;         // 256*512
constexpr size_t O_NLL    = 131072;    // 256
constexpr size_t O_KL     = 131328;    // 256
constexpr size_t O_LOGITS = 131584;    // 256*16
constexpr size_t O_VALUES = 135680;    // 256
constexpr size_t O_MUQ    = 135936;    // 256*128
constexpr size_t O_LVQ    = 168704;    // 256*128
constexpr size_t O_Z      = 201472;    // 256*128
constexpr size_t O_VGAT   = 234240;    // 256*256

// workspace offsets (floats)
constexpr size_t W_T1    = 0;          // 256*512
constexpr size_t W_T2    = 131072;     // 256*512
constexpr size_t W_T3    = 262144;     // 256*512
constexpr size_t W_PBUF  = 393216;     // 256*256
constexpr size_t W_QBUF  = 458752;     // 256*256
constexpr size_t W_XBUF  = 524288;     // 256*512
constexpr size_t W_GI    = 655360;     // 256*1536
constexpr size_t W_GH    = 1048576;    // 256*1536
constexpr size_t W_WH1   = 1441792;    // 256*256
constexpr size_t W_WH2   = 1507328;    // 256*256
constexpr size_t W_H1    = 1572864;    // 256*256
constexpr size_t W_ALPHA = 1638400;    // 256*256
constexpr size_t W_CN    = 1703936;    // 256
constexpr size_t W_A1    = 1704192;    // 256
constexpr size_t W_B1    = 1704448;    // 256
constexpr size_t W_A2    = 1704704;    // 256
constexpr size_t W_B2    = 1704960;    // 256
constexpr size_t W_HA    = 1705216;    // 256*256
constexpr size_t W_HC    = 1770752;    // 256*256
constexpr size_t W_RED   = 1836288;    // 258: S1[128], S2[128], C, SS

#define DI __device__ __forceinline__

DI float sigm(float x)    { return 1.f / (1.f + expf(-x)); }
DI float clamp10(float x) { return fminf(fmaxf(x, -10.f), 10.f); }

// ---------------- multi-GEMM: C = act(A @ W^T + b), block-specialized ----------------
// A row = [A1 row (K1) | A2 row (K2)], W is (Nn, K) row-major, M = 256.
// BM=BN=64, BK=16, 256 threads, 4x4 microtile.
struct GDesc {
    const float* A1; const float* A2; const float* W; const float* bias;
    float* C; int K1, K2, Nn, act, xt;   // xt = Nn/64
};

DI void gemm_body(const GDesc g, int bx, int by,
                  float (*As)[68], float (*Ws)[68])
{
    const int K = g.K1 + g.K2;
    int tid = threadIdx.x;
    int tx = tid & 15, ty = tid >> 4;
    int n0 = bx * 64, m0 = by * 64;
    int lk = tid & 15, lr = tid >> 4;
    float acc[4][4] = {};
    for (int k0 = 0; k0 < K; k0 += 16) {
        int kg = k0 + lk;
        #pragma unroll
        for (int p = 0; p < 4; ++p) {
            int r = lr + p * 16;
            int row = m0 + r;
            float av = (kg < g.K1) ? g.A1[(size_t)row * g.K1 + kg]
                                   : g.A2[(size_t)row * g.K2 + (kg - g.K1)];
            As[lk][r] = av;
            Ws[lk][r] = g.W[(size_t)(n0 + r) * K + kg];
        }
        __syncthreads();
        #pragma unroll
        for (int kk = 0; kk < 16; ++kk) {
            float4 a4 = *(const float4*)&As[kk][ty * 4];
            float4 b4 = *(const float4*)&Ws[kk][tx * 4];
            float a_[4] = {a4.x, a4.y, a4.z, a4.w};
            float b_[4] = {b4.x, b4.y, b4.z, b4.w};
            #pragma unroll
            for (int i = 0; i < 4; ++i)
                #pragma unroll
                for (int j = 0; j < 4; ++j)
                    acc[i][j] = fmaf(a_[i], b_[j], acc[i][j]);
        }
        __syncthreads();
    }
    #pragma unroll
    for (int i = 0; i < 4; ++i) {
        int row = m0 + ty * 4 + i;
        int col = n0 + tx * 4;
        float4 o;
        float* po = &o.x;
        #pragma unroll
        for (int j = 0; j < 4; ++j) {
            float v = acc[i][j] + (g.bias ? g.bias[col + j] : 0.f);
            if (g.act) v = fmaxf(v, 0.f);
            po[j] = v;
        }
        *(float4*)&g.C[(size_t)row * g.Nn + col] = o;
    }
}

__global__ __launch_bounds__(256) void mgemm3(GDesc a, GDesc b, GDesc c) {
    __shared__ __align__(16) float As[16][68];
    __shared__ __align__(16) float Ws[16][68];
    int bx = blockIdx.x;
    if (bx < a.xt)                gemm_body(a, bx, blockIdx.y, As, Ws);
    else if (bx < a.xt + b.xt)    gemm_body(b, bx - a.xt, blockIdx.y, As, Ws);
    else                          gemm_body(c, bx - a.xt - b.xt, blockIdx.y, As, Ws);
}

__global__ __launch_bounds__(256) void mgemm2(GDesc a, GDesc b) {
    __shared__ __align__(16) float As[16][68];
    __shared__ __align__(16) float Ws[16][68];
    int bx = blockIdx.x;
    if (bx < a.xt) gemm_body(a, bx, blockIdx.y, As, Ws);
    else           gemm_body(b, bx - a.xt, blockIdx.y, As, Ws);
}

__global__ __launch_bounds__(256) void mgemm1(GDesc a) {
    __shared__ __align__(16) float As[16][68];
    __shared__ __align__(16) float Ws[16][68];
    gemm_body(a, blockIdx.x, blockIdx.y, As, Ws);
}

// ---------------- GEMM NN: C = act(A @ B), B is (K, N) row-major ----------------
template<int ACTMODE>   // 0 none, 2 elu
__global__ __launch_bounds__(256) void gemm_nn(
    const float* __restrict__ A, const float* __restrict__ B,
    float* __restrict__ C, int Nn, int K)
{
    __shared__ __align__(16) float As[16][68];
    __shared__ __align__(16) float Bs[16][68];
    int tid = threadIdx.x;
    int tx = tid & 15, ty = tid >> 4;
    int n0 = blockIdx.x * 64, m0 = blockIdx.y * 64;
    int lk = tid & 15, lr = tid >> 4;
    int bc = tid & 63, bk0 = tid >> 6;
    float acc[4][4] = {};
    for (int k0 = 0; k0 < K; k0 += 16) {
        #pragma unroll
        for (int p = 0; p < 4; ++p) {
            int r = lr + p * 16;
            As[lk][r] = A[(size_t)(m0 + r) * K + k0 + lk];
            int kk = bk0 * 4 + p;
            Bs[kk][bc] = B[(size_t)(k0 + kk) * Nn + n0 + bc];
        }
        __syncthreads();
        #pragma unroll
        for (int kk = 0; kk < 16; ++kk) {
            float4 a4 = *(const float4*)&As[kk][ty * 4];
            float4 b4 = *(const float4*)&Bs[kk][tx * 4];
            float a_[4] = {a4.x, a4.y, a4.z, a4.w};
            float b_[4] = {b4.x, b4.y, b4.z, b4.w};
            #pragma unroll
            for (int i = 0; i < 4; ++i)
                #pragma unroll
                for (int j = 0; j < 4; ++j)
                    acc[i][j] = fmaf(a_[i], b_[j], acc[i][j]);
        }
        __syncthreads();
    }
    #pragma unroll
    for (int i = 0; i < 4; ++i) {
        int row = m0 + ty * 4 + i;
        int col = n0 + tx * 4;
        float4 o;
        float* po = &o.x;
        #pragma unroll
        for (int j = 0; j < 4; ++j) {
            float v = acc[i][j];
            if (ACTMODE == 2) v = v > 0.f ? v : expf(v) - 1.f;
            po[j] = v;
        }
        *(float4*)&C[(size_t)row * Nn + col] = o;
    }
}

// ---------------- zero the reduction scratch ----------------
__global__ __launch_bounds__(320) void zero_k(float* __restrict__ p) {
    int tid = threadIdx.x;
    if (tid < 258) p[tid] = 0.f;
}

// ---------------- VRNN post: mu_q/lv_q/z to out, kl rowwise ----------------
__global__ __launch_bounds__(128) void post_pq(
    const float* __restrict__ pbuf, const float* __restrict__ qbuf,
    const float* __restrict__ eps, float* __restrict__ out)
{
    int i = blockIdx.x, tid = threadIdx.x;   // tid = d in [0,128)
    float mu_p = pbuf[(size_t)i * 256 + tid];
    float lv_p = clamp10(pbuf[(size_t)i * 256 + 128 + tid]);
    float mu_q = qbuf[(size_t)i * 256 + tid];
    float lv_q = clamp10(qbuf[(size_t)i * 256 + 128 + tid]);
    float z = mu_q + eps[(size_t)i * 128 + tid] * expf(0.5f * lv_q);
    out[O_MUQ + (size_t)i * 128 + tid] = mu_q;
    out[O_LVQ + (size_t)i * 128 + tid] = lv_q;
    out[O_Z   + (size_t)i * 128 + tid] = z;
    float ivp = expf(-lv_p);
    float dm = mu_q - mu_p;
    float t = dm * dm * ivp + expf(lv_q) * ivp + (lv_p - lv_q) - 1.f;
    __shared__ float red[2];
    #pragma unroll
    for (int off = 32; off; off >>= 1) t += __shfl_down(t, off);
    if ((tid & 63) == 0) red[tid >> 6] = t;
    __syncthreads();
    if (tid == 0) out[O_KL + i] = 0.5f * (red[0] + red[1]);
}

// ---------------- nll rowwise ----------------
__global__ __launch_bounds__(256) void nll_k(
    const float* __restrict__ xbuf, const float* __restrict__ obs,
    float* __restrict__ out)
{
    int i = blockIdx.x, tid = threadIdx.x;   // tid = d in [0,256)
    float mu = xbuf[(size_t)i * 512 + tid];
    float lv = clamp10(xbuf[(size_t)i * 512 + 256 + tid]);
    float d = obs[(size_t)i * 256 + tid] - mu;
    float t = d * d * expf(-lv) + lv;
    __shared__ float red[4];
    #pragma unroll
    for (int off = 32; off; off >>= 1) t += __shfl_down(t, off);
    if ((tid & 63) == 0) red[tid >> 6] = t;
    __syncthreads();
    if (tid == 0) out[O_NLL + i] = 0.5f * (red[0] + red[1] + red[2] + red[3]);
}

// ---------------- GRU gates ----------------
__global__ __launch_bounds__(256) void gru_k(
    const float* __restrict__ gi, const float* __restrict__ gh,
    const float* __restrict__ h_prev, float* __restrict__ out)
{
    int idx = blockIdx.x * 256 + threadIdx.x;
    int i = idx >> 9, h = idx & 511;
    const float* gir = gi + (size_t)i * 1536;
    const float* ghr = gh + (size_t)i * 1536;
    float r = sigm(gir[h] + ghr[h]);
    float u = sigm(gir[512 + h] + ghr[512 + h]);
    float c = tanhf(gir[1024 + h] + r * ghr[1024 + h]);
    float hp = h_prev[(size_t)i * 512 + h];
    out[O_HNEW + (size_t)i * 512 + h] = (1.f - u) * c + u * hp;
}

// ---------------- coop pass 1: S1[d], S2[d], C, SS via atomics (32 blocks) ----------------
__global__ __launch_bounds__(256) void coop_red_k(
    const float* __restrict__ out, float* __restrict__ red)
{
    int tid = threadIdx.x;
    int d = tid & 127, pair = tid >> 7;
    int b = blockIdx.x;                       // 0..31, agents b*8..b*8+7
    float s1 = 0.f, s2 = 0.f, c = 0.f, ss = 0.f;
    #pragma unroll
    for (int jj = 0; jj < 4; ++jj) {
        int i = b * 8 + jj * 2 + pair;
        float mu = out[O_MUQ + (size_t)i * 128 + d];
        float lv = out[O_LVQ + (size_t)i * 128 + d];
        float iv = expf(-lv);
        s1 += iv; s2 += mu * iv; c += mu * mu * iv; ss += lv;
    }
    atomicAdd(&red[d], s1);
    atomicAdd(&red[128 + d], s2);
    #pragma unroll
    for (int off = 32; off; off >>= 1) {
        c  += __shfl_down(c, off);
        ss += __shfl_down(ss, off);
    }
    if ((tid & 63) == 0) {
        atomicAdd(&red[256], c);
        atomicAdd(&red[257], ss);
    }
}

// ---------------- coop pass 2: per-agent coop -> cn (16 blocks, 16 lanes/agent) ----------------
__global__ __launch_bounds__(256) void coop_cn_k(
    const float* __restrict__ out, const float* __restrict__ red,
    const float* __restrict__ cw, const float* __restrict__ cb,
    float* __restrict__ cn)
{
    int tid = threadIdx.x;
    int a = (blockIdx.x << 4) + (tid >> 4);
    int s = tid & 15;
    const float* mur = out + O_MUQ + (size_t)a * 128 + s * 8;
    const float* lvr = out + O_LVQ + (size_t)a * 128 + s * 8;
    float acc1 = 0.f, acc2 = 0.f, slv = 0.f;
    #pragma unroll
    for (int j = 0; j < 8; ++j) {
        float mu = mur[j], lv = lvr[j];
        acc1 += (mu * mu + expf(lv)) * red[s * 8 + j];
        acc2 += mu * red[128 + s * 8 + j];
        slv  += lv;
    }
    #pragma unroll
    for (int m = 1; m < 16; m <<= 1) {
        acc1 += __shfl_xor(acc1, m);
        acc2 += __shfl_xor(acc2, m);
        slv  += __shfl_xor(slv, m);
    }
    if (s == 0) {
        float coop = 0.5f * (acc1 - 2.f * acc2 + red[256] + red[257]
                             - 256.f * slv - 32768.f) / 255.f;
        cn[a] = sigm(cw[0] * coop + cb[0]);
    }
}

// ---------------- GAT a/b vectors (16 blocks, 16 lanes/agent) ----------------
__global__ __launch_bounds__(256) void gat_ab_k(
    const float* __restrict__ Wh, const float* __restrict__ asrc,
    const float* __restrict__ adst, const float* __restrict__ cn,
    float* __restrict__ a, float* __restrict__ b)
{
    int tid = threadIdx.x;
    int i = (blockIdx.x << 4) + (tid >> 4);
    int s = tid & 15;
    const float4* wr = (const float4*)(Wh + (size_t)i * 256 + s * 16);
    const float4* s4 = (const float4*)(asrc + s * 16);
    const float4* d4 = (const float4*)(adst + s * 16);
    float sa = 0.f, sb = 0.f;
    #pragma unroll
    for (int q = 0; q < 4; ++q) {
        float4 w = wr[q], sv = s4[q], dv = d4[q];
        sa += w.x * sv.x + w.y * sv.y + w.z * sv.z + w.w * sv.w;
        sb += w.x * dv.x + w.y * dv.y + w.z * dv.z + w.w * dv.w;
    }
    #pragma unroll
    for (int m = 1; m < 16; m <<= 1) {
        sa += __shfl_xor(sa, m);
        sb += __shfl_xor(sb, m);
    }
    if (s == 0) {
        float c = cn[i];
        a[i] = sa + c;
        b[i] = sb + c;
    }
}

// ---------------- GAT softmax rows: alpha = softmax_j(lrelu(a_i + b_j)) ----------------
__global__ __launch_bounds__(256) void gat_softmax_k(
    const float* __restrict__ a, const float* __restrict__ b,
    float* __restrict__ alpha)
{
    __shared__ float bsh[256];
    __shared__ float ash[16];
    int tid = threadIdx.x;
    int b0 = blockIdx.x * 16;
    bsh[tid] = b[tid];
    if (tid < 16) ash[tid] = a[b0 + tid];
    __syncthreads();
    int li = tid >> 4, jg = tid & 15;
    float ai = ash[li];
    float e[16];
    float m = -1e30f;
    #pragma unroll
    for (int q = 0; q < 16; ++q) {
        float s = ai + bsh[jg * 16 + q];
        s = s > 0.f ? s : 0.2f * s;
        e[q] = s;
        m = fmaxf(m, s);
    }
    #pragma unroll
    for (int msk = 1; msk < 16; msk <<= 1) m = fmaxf(m, __shfl_xor(m, msk, 16));
    float sum = 0.f;
    #pragma unroll
    for (int q = 0; q < 16; ++q) { e[q] = expf(e[q] - m); sum += e[q]; }
    #pragma unroll
    for (int msk = 1; msk < 16; msk <<= 1) sum += __shfl_xor(sum, msk, 16);
    float inv = 1.f / sum;
    int i = b0 + li;
    float4* dst = (float4*)(alpha + (size_t)i * 256 + jg * 16);
    dst[0] = make_float4(e[0] * inv, e[1] * inv, e[2] * inv, e[3] * inv);
    dst[1] = make_float4(e[4] * inv, e[5] * inv, e[6] * inv, e[7] * inv);
    dst[2] = make_float4(e[8] * inv, e[9] * inv, e[10] * inv, e[11] * inv);
    dst[3] = make_float4(e[12] * inv, e[13] * inv, e[14] * inv, e[15] * inv);
}

// ---------------- per-agent head hidden layers (BW stream, 4-row batches) ----------------
// grid = 2048: n(256) x which(2) x quarter(4). 4 waves/block, wave owns 16 rows.
__global__ __launch_bounds__(256) void heads_hidden_k(
    const float* __restrict__ obs, const float* __restrict__ vgat,
    const float* __restrict__ Wa1, const float* __restrict__ ba1,
    const float* __restrict__ Wc1, const float* __restrict__ bc1,
    float* __restrict__ ha, float* __restrict__ hc)
{
    int bid = blockIdx.x;
    int n = bid >> 3;
    int which = (bid >> 2) & 1;
    int q = bid & 3;
    int tid = threadIdx.x;
    int wave = tid >> 6, lane = tid & 63;
    const float* Wb = (which ? Wc1 : Wa1) + (size_t)n * 131072;
    const float* bb = (which ? bc1 : ba1) + (size_t)n * 256;
    float* hb = (which ? hc : ha) + (size_t)n * 256;
    // x[lane*8 .. lane*8+7]: lanes 0-31 -> obs, lanes 32-63 -> vgat
    float4 x0, x1;
    if (lane < 32) {
        const float4* s = (const float4*)(obs + (size_t)n * 256 + lane * 8);
        x0 = s[0]; x1 = s[1];
    } else {
        const float4* s = (const float4*)(vgat + (size_t)n * 256 + (lane - 32) * 8);
        x0 = s[0]; x1 = s[1];
    }
    int row0 = q * 64 + wave * 16;
    for (int rb = 0; rb < 16; rb += 4) {
        float v[4];
        #pragma unroll
        for (int rr = 0; rr < 4; ++rr) {
            const float4* wr = (const float4*)(Wb + (size_t)(row0 + rb + rr) * 512 + lane * 8);
            float4 w0 = wr[0], w1 = wr[1];
            v[rr] = w0.x * x0.x + w0.y * x0.y + w0.z * x0.z + w0.w * x0.w
                  + w1.x * x1.x + w1.y * x1.y + w1.z * x1.z + w1.w * x1.w;
        }
        #pragma unroll
        for (int off = 32; off; off >>= 1) {
            #pragma unroll
            for (int rr = 0; rr < 4; ++rr) v[rr] += __shfl_down(v[rr], off);
        }
        if (lane == 0) {
            #pragma unroll
            for (int rr = 0; rr < 4; ++rr) {
                int row = row0 + rb + rr;
                hb[row] = fmaxf(v[rr] + bb[row], 0.f);
            }
        }
    }
}

// ---------------- head output layers ----------------
__global__ __launch_bounds__(256) void heads_out_k(
    const float* __restrict__ ha, const float* __restrict__ hc,
    const float* __restrict__ Wa2, const float* __restrict__ ba2,
    const float* __restrict__ Wc2, const float* __restrict__ bc2,
    float* __restrict__ out)
{
    int n = blockIdx.x, tid = threadIdx.x;
    __shared__ __align__(16) float hA[256], hC[256];
    hA[tid] = ha[(size_t)n * 256 + tid];
    hC[tid] = hc[(size_t)n * 256 + tid];
    __syncthreads();
    int wave = tid >> 6, lane = tid & 63;
    const float4* h4 = (const float4*)hA;
    float4 hv = h4[lane];
    for (int o = wave; o < 16; o += 4) {
        const float4* w4 = (const float4*)(Wa2 + ((size_t)n * 16 + o) * 256);
        float4 wv = w4[lane];
        float v = wv.x * hv.x + wv.y * hv.y + wv.z * hv.z + wv.w * hv.w;
        #pragma unroll
        for (int off = 32; off; off >>= 1) v += __shfl_down(v, off);
        if (lane == 0) out[O_LOGITS + (size_t)n * 16 + o] = v + ba2[(size_t)n * 16 + o];
    }
    if (wave == 0) {
        const float4* w4 = (const float4*)(Wc2 + (size_t)n * 256);
        const float4* h4c = (const float4*)hC;
        float4 wv = w4[lane], hcv = h4c[lane];
        float v = wv.x * hcv.x + wv.y * hcv.y + wv.z * hcv.z + wv.w * hcv.w;
        #pragma unroll
        for (int off = 32; off; off >>= 1) v += __shfl_down(v, off);
        if (lane == 0) out[O_VALUES + n] = v + bc2[n];
    }
}

// ---------------- launch ----------------
extern "C" void kernel_launch(void* const* d_in, const int* in_sizes, int n_in,
                              void* d_out_v, int out_size, void* d_ws, size_t ws_size,
                              hipStream_t stream)
{
    const float* obs   = (const float*)d_in[0];
    const float* h_prev= (const float*)d_in[1];
    const float* eps   = (const float*)d_in[2];
    const float* Wp1 = (const float*)d_in[3];  const float* bp1 = (const float*)d_in[4];
    const float* Wp2 = (const float*)d_in[5];  const float* bp2 = (const float*)d_in[6];
    const float* We1 = (const float*)d_in[7];  const float* be1 = (const float*)d_in[8];
    const float* We2 = (const float*)d_in[9];  const float* be2 = (const float*)d_in[10];
    const float* Wd1 = (const float*)d_in[11]; const float* bd1 = (const float*)d_in[12];
    const float* Wd2 = (const float*)d_in[13]; const float* bd2 = (const float*)d_in[14];
    const float* Wih = (const float*)d_in[15]; const float* Whh = (const float*)d_in[16];
    const float* bih = (const float*)d_in[17]; const float* bhh = (const float*)d_in[18];
    const float* Wg1 = (const float*)d_in[19]; const float* as1 = (const float*)d_in[20];
    const float* ad1 = (const float*)d_in[21];
    const float* Wg2 = (const float*)d_in[22]; const float* as2 = (const float*)d_in[23];
    const float* ad2 = (const float*)d_in[24];
    const float* cw  = (const float*)d_in[25]; const float* cb  = (const float*)d_in[26];
    const float* Wa1 = (const float*)d_in[27]; const float* ba1 = (const float*)d_in[28];
    const float* Wa2 = (const float*)d_in[29]; const float* ba2 = (const float*)d_in[30];
    const float* Wc1 = (const float*)d_in[31]; const float* bc1 = (const float*)d_in[32];
    const float* Wc2 = (const float*)d_in[33]; const float* bc2 = (const float*)d_in[34];
    float* out = (float*)d_out_v;
    float* ws  = (float*)d_ws;
    dim3 blk(256);

    // zero reduction scratch (no deps)
    zero_k<<<dim3(1), dim3(320), 0, stream>>>(ws + W_RED);

    // S1: t1 = relu(h@Wp1+b), t2 = relu([obs,h]@We1+b), gh = h@Whh+bhh  (one launch)
    GDesc dt1 = {h_prev, nullptr, Wp1, bp1, ws + W_T1, 512, 0,   512, 1, 8};
    GDesc dt2 = {obs,    h_prev,  We1, be1, ws + W_T2, 256, 512, 512, 1, 8};
    GDesc dgh = {h_prev, nullptr, Whh, bhh, ws + W_GH, 512, 0,  1536, 0, 24};
    mgemm3<<<dim3(40, 4), blk, 0, stream>>>(dt1, dt2, dgh);

    // S2: pbuf = t1@Wp2+b, qbuf = t2@We2+b
    GDesc dp = {ws + W_T1, nullptr, Wp2, bp2, ws + W_PBUF, 512, 0, 256, 0, 4};
    GDesc dq = {ws + W_T2, nullptr, We2, be2, ws + W_QBUF, 512, 0, 256, 0, 4};
    mgemm2<<<dim3(8, 4), blk, 0, stream>>>(dp, dq);

    // mu_q / lv_q / z / kl
    post_pq<<<dim3(256), dim3(128), 0, stream>>>(ws + W_PBUF, ws + W_QBUF, eps, out);

    // coop reduction (depends only on mu_q/lv_q)
    coop_red_k<<<dim3(32), blk, 0, stream>>>(out, ws + W_RED);
    coop_cn_k<<<dim3(16), blk, 0, stream>>>(out, ws + W_RED, cw, cb, ws + W_CN);

    // S3: t3 = relu([z,h]@Wd1+b), gi = [obs,z]@Wih+bih
    GDesc dt3 = {out + O_Z, h_prev,    Wd1, bd1, ws + W_T3, 128, 512, 512, 1, 8};
    GDesc dgi = {obs,       out + O_Z, Wih, bih, ws + W_GI, 256, 128, 1536, 0, 24};
    mgemm2<<<dim3(32, 4), blk, 0, stream>>>(dt3, dgi);

    // S4: xbuf = t3@Wd2+b
    GDesc dx = {ws + W_T3, nullptr, Wd2, bd2, ws + W_XBUF, 512, 0, 512, 0, 8};
    mgemm1<<<dim3(8, 4), blk, 0, stream>>>(dx);
    nll_k<<<dim3(256), blk, 0, stream>>>(ws + W_XBUF, obs, out);

    // GRU -> h_new
    gru_k<<<dim3(512), blk, 0, stream>>>(ws + W_GI, ws + W_GH, h_prev, out);

    // GAT stage 1
    GDesc dw1 = {out + O_HNEW, nullptr, Wg1, nullptr, ws + W_WH1, 512, 0, 256, 0, 4};
    mgemm1<<<dim3(4, 4), blk, 0, stream>>>(dw1);
    gat_ab_k<<<dim3(16), blk, 0, stream>>>(ws + W_WH1, as1, ad1, ws + W_CN, ws + W_A1, ws + W_B1);
    gat_softmax_k<<<dim3(16), blk, 0, stream>>>(ws + W_A1, ws + W_B1, ws + W_ALPHA);
    gemm_nn<2><<<dim3(4, 4), blk, 0, stream>>>(ws + W_ALPHA, ws + W_WH1, ws + W_H1, 256, 256);

    // GAT stage 2
    GDesc dw2 = {ws + W_H1, nullptr, Wg2, nullptr, ws + W_WH2, 256, 0, 256, 0, 4};
    mgemm1<<<dim3(4, 4), blk, 0, stream>>>(dw2);
    gat_ab_k<<<dim3(16), blk, 0, stream>>>(ws + W_WH2, as2, ad2, ws + W_CN, ws + W_A2, ws + W_B2);
    gat_softmax_k<<<dim3(16), blk, 0, stream>>>(ws + W_A2, ws + W_B2, ws + W_ALPHA);
    gemm_nn<2><<<dim3(4, 4), blk, 0, stream>>>(ws + W_ALPHA, ws + W_WH2, out + O_VGAT, 256, 256);

    // per-agent actor/critic heads
    heads_hidden_k<<<dim3(2048), blk, 0, stream>>>(obs, out + O_VGAT, Wa1, ba1, Wc1, bc1,
                                                   ws + W_HA, ws + W_HC);
    heads_out_k<<<dim3(256), blk, 0, stream>>>(ws + W_HA, ws + W_HC, Wa2, ba2, Wc2, bc2, out);
}

// Round 8
// 601.185 us; speedup vs baseline: 1.3911x; 1.0849x over previous
//
#include <hip/hip_runtime.h>
#include <cstddef>

// ---------------- constants / layout ----------------
// N=256, OBS=256, ACT=16, H=512, Z=128, G=256, IN=512, HID=256
constexpr size_t O_HNEW   = 0;         // 256*512
constexpr size_t O_NLL    = 131072;    // 256
constexpr size_t O_KL     = 131328;    // 256
constexpr size_t O_LOGITS = 131584;    // 256*16
constexpr size_t O_VALUES = 135680;    // 256
constexpr size_t O_MUQ    = 135936;    // 256*128
constexpr size_t O_LVQ    = 168704;    // 256*128
constexpr size_t O_Z      = 201472;    // 256*128
constexpr size_t O_VGAT   = 234240;    // 256*256

// workspace offsets (floats)
constexpr size_t W_T1    = 0;          // 256*512
constexpr size_t W_T2    = 131072;     // 256*512
constexpr size_t W_T3    = 262144;     // 256*512
constexpr size_t W_PBUF  = 393216;     // 256*256
constexpr size_t W_QBUF  = 458752;     // 256*256
constexpr size_t W_XBUF  = 524288;     // 256*512
constexpr size_t W_GI    = 655360;     // 256*1536
constexpr size_t W_GH    = 1048576;    // 256*1536
constexpr size_t W_WH1   = 1441792;    // 256*256
constexpr size_t W_WH2   = 1507328;    // 256*256
constexpr size_t W_H1    = 1572864;    // 256*256
constexpr size_t W_ALPHA = 1638400;    // 256*256
constexpr size_t W_CN    = 1703936;    // 256
constexpr size_t W_A1    = 1704192;    // 256
constexpr size_t W_B1    = 1704448;    // 256
constexpr size_t W_A2    = 1704704;    // 256
constexpr size_t W_B2    = 1704960;    // 256
constexpr size_t W_HA    = 1705216;    // 256*256
constexpr size_t W_HC    = 1770752;    // 256*256
constexpr size_t W_RED   = 1836288;    // 258: S1[128], S2[128], C, SS

#define DI __device__ __forceinline__

DI float sigm(float x)    { return 1.f / (1.f + expf(-x)); }
DI float clamp10(float x) { return fminf(fmaxf(x, -10.f), 10.f); }

// ---------------- multi-GEMM: C = act(A @ W^T + b), block-specialized ----------------
// A row = [A1 row (K1) | A2 row (K2)], W is (Nn, K) row-major, M = 256.
// BM=BN=64, BK=16, 256 threads, 4x4 microtile. K1 always multiple of 128.
struct GDesc {
    const float* A1; const float* A2; const float* W; const float* bias;
    float* C; int K1, K2, Nn, act, xt;   // xt = Nn/64
};

DI void gemm_body(const GDesc g, int bx, int by,
                  float (*As)[68], float (*Ws)[68])
{
    const int K = g.K1 + g.K2;
    int tid = threadIdx.x;
    int tx = tid & 15, ty = tid >> 4;
    int n0 = bx * 64, m0 = by * 64;
    int tr = tid >> 2, tc = tid & 3;          // tr: tile row/col 0..63, tc: float4 slot
    float acc[4][4] = {};
    for (int k0 = 0; k0 < K; k0 += 16) {
        int kg = k0 + tc * 4;
        float4 av;
        {
            int row = m0 + tr;
            if (kg < g.K1) av = *(const float4*)&g.A1[(size_t)row * g.K1 + kg];
            else           av = *(const float4*)&g.A2[(size_t)row * g.K2 + (kg - g.K1)];
        }
        float4 wv = *(const float4*)&g.W[(size_t)(n0 + tr) * K + kg];
        As[tc * 4 + 0][tr] = av.x; As[tc * 4 + 1][tr] = av.y;
        As[tc * 4 + 2][tr] = av.z; As[tc * 4 + 3][tr] = av.w;
        Ws[tc * 4 + 0][tr] = wv.x; Ws[tc * 4 + 1][tr] = wv.y;
        Ws[tc * 4 + 2][tr] = wv.z; Ws[tc * 4 + 3][tr] = wv.w;
        __syncthreads();
        #pragma unroll
        for (int kk = 0; kk < 16; ++kk) {
            float4 a4 = *(const float4*)&As[kk][ty * 4];
            float4 b4 = *(const float4*)&Ws[kk][tx * 4];
            float a_[4] = {a4.x, a4.y, a4.z, a4.w};
            float b_[4] = {b4.x, b4.y, b4.z, b4.w};
            #pragma unroll
            for (int i = 0; i < 4; ++i)
                #pragma unroll
                for (int j = 0; j < 4; ++j)
                    acc[i][j] = fmaf(a_[i], b_[j], acc[i][j]);
        }
        __syncthreads();
    }
    #pragma unroll
    for (int i = 0; i < 4; ++i) {
        int row = m0 + ty * 4 + i;
        int col = n0 + tx * 4;
        float4 o;
        float* po = &o.x;
        #pragma unroll
        for (int j = 0; j < 4; ++j) {
            float v = acc[i][j] + (g.bias ? g.bias[col + j] : 0.f);
            if (g.act) v = fmaxf(v, 0.f);
            po[j] = v;
        }
        *(float4*)&g.C[(size_t)row * g.Nn + col] = o;
    }
}

__global__ __launch_bounds__(256) void mgemm3(GDesc a, GDesc b, GDesc c) {
    __shared__ __align__(16) float As[16][68];
    __shared__ __align__(16) float Ws[16][68];
    int bx = blockIdx.x;
    if (bx < a.xt)                gemm_body(a, bx, blockIdx.y, As, Ws);
    else if (bx < a.xt + b.xt)    gemm_body(b, bx - a.xt, blockIdx.y, As, Ws);
    else                          gemm_body(c, bx - a.xt - b.xt, blockIdx.y, As, Ws);
}

__global__ __launch_bounds__(256) void mgemm2(GDesc a, GDesc b) {
    __shared__ __align__(16) float As[16][68];
    __shared__ __align__(16) float Ws[16][68];
    int bx = blockIdx.x;
    if (bx < a.xt) gemm_body(a, bx, blockIdx.y, As, Ws);
    else           gemm_body(b, bx - a.xt, blockIdx.y, As, Ws);
}

__global__ __launch_bounds__(256) void mgemm1(GDesc a) {
    __shared__ __align__(16) float As[16][68];
    __shared__ __align__(16) float Ws[16][68];
    gemm_body(a, blockIdx.x, blockIdx.y, As, Ws);
}

// ---------------- GEMM NN: C = act(A @ B), B is (K, N) row-major ----------------
template<int ACTMODE>   // 0 none, 2 elu
__global__ __launch_bounds__(256) void gemm_nn(
    const float* __restrict__ A, const float* __restrict__ B,
    float* __restrict__ C, int Nn, int K)
{
    __shared__ __align__(16) float As[16][68];
    __shared__ __align__(16) float Bs[16][68];
    int tid = threadIdx.x;
    int tx = tid & 15, ty = tid >> 4;
    int n0 = blockIdx.x * 64, m0 = blockIdx.y * 64;
    int tr = tid >> 2, tc = tid & 3;
    int bc = tid & 63, bk0 = tid >> 6;
    float acc[4][4] = {};
    for (int k0 = 0; k0 < K; k0 += 16) {
        int kg = k0 + tc * 4;
        float4 av = *(const float4*)&A[(size_t)(m0 + tr) * K + kg];
        As[tc * 4 + 0][tr] = av.x; As[tc * 4 + 1][tr] = av.y;
        As[tc * 4 + 2][tr] = av.z; As[tc * 4 + 3][tr] = av.w;
        #pragma unroll
        for (int p = 0; p < 4; ++p) {
            int kk = bk0 * 4 + p;
            Bs[kk][bc] = B[(size_t)(k0 + kk) * Nn + n0 + bc];
        }
        __syncthreads();
        #pragma unroll
        for (int kk = 0; kk < 16; ++kk) {
            float4 a4 = *(const float4*)&As[kk][ty * 4];
            float4 b4 = *(const float4*)&Bs[kk][tx * 4];
            float a_[4] = {a4.x, a4.y, a4.z, a4.w};
            float b_[4] = {b4.x, b4.y, b4.z, b4.w};
            #pragma unroll
            for (int i = 0; i < 4; ++i)
                #pragma unroll
                for (int j = 0; j < 4; ++j)
                    acc[i][j] = fmaf(a_[i], b_[j], acc[i][j]);
        }
        __syncthreads();
    }
    #pragma unroll
    for (int i = 0; i < 4; ++i) {
        int row = m0 + ty * 4 + i;
        int col = n0 + tx * 4;
        float4 o;
        float* po = &o.x;
        #pragma unroll
        for (int j = 0; j < 4; ++j) {
            float v = acc[i][j];
            if (ACTMODE == 2) v = v > 0.f ? v : expf(v) - 1.f;
            po[j] = v;
        }
        *(float4*)&C[(size_t)row * Nn + col] = o;
    }
}

// ---------------- zero the reduction scratch ----------------
__global__ __launch_bounds__(320) void zero_k(float* __restrict__ p) {
    int tid = threadIdx.x;
    if (tid < 258) p[tid] = 0.f;
}

// ---------------- VRNN post: mu_q/lv_q/z to out, kl rowwise ----------------
__global__ __launch_bounds__(128) void post_pq(
    const float* __restrict__ pbuf, const float* __restrict__ qbuf,
    const float* __restrict__ eps, float* __restrict__ out)
{
    int i = blockIdx.x, tid = threadIdx.x;   // tid = d in [0,128)
    float mu_p = pbuf[(size_t)i * 256 + tid];
    float lv_p = clamp10(pbuf[(size_t)i * 256 + 128 + tid]);
    float mu_q = qbuf[(size_t)i * 256 + tid];
    float lv_q = clamp10(qbuf[(size_t)i * 256 + 128 + tid]);
    float z = mu_q + eps[(size_t)i * 128 + tid] * expf(0.5f * lv_q);
    out[O_MUQ + (size_t)i * 128 + tid] = mu_q;
    out[O_LVQ + (size_t)i * 128 + tid] = lv_q;
    out[O_Z   + (size_t)i * 128 + tid] = z;
    float ivp = expf(-lv_p);
    float dm = mu_q - mu_p;
    float t = dm * dm * ivp + expf(lv_q) * ivp + (lv_p - lv_q) - 1.f;
    __shared__ float red[2];
    #pragma unroll
    for (int off = 32; off; off >>= 1) t += __shfl_down(t, off);
    if ((tid & 63) == 0) red[tid >> 6] = t;
    __syncthreads();
    if (tid == 0) out[O_KL + i] = 0.5f * (red[0] + red[1]);
}

// ---------------- nll rowwise ----------------
__global__ __launch_bounds__(256) void nll_k(
    const float* __restrict__ xbuf, const float* __restrict__ obs,
    float* __restrict__ out)
{
    int i = blockIdx.x, tid = threadIdx.x;   // tid = d in [0,256)
    float mu = xbuf[(size_t)i * 512 + tid];
    float lv = clamp10(xbuf[(size_t)i * 512 + 256 + tid]);
    float d = obs[(size_t)i * 256 + tid] - mu;
    float t = d * d * expf(-lv) + lv;
    __shared__ float red[4];
    #pragma unroll
    for (int off = 32; off; off >>= 1) t += __shfl_down(t, off);
    if ((tid & 63) == 0) red[tid >> 6] = t;
    __syncthreads();
    if (tid == 0) out[O_NLL + i] = 0.5f * (red[0] + red[1] + red[2] + red[3]);
}

// ---------------- GRU gates (float4) ----------------
__global__ __launch_bounds__(256) void gru_k(
    const float* __restrict__ gi, const float* __restrict__ gh,
    const float* __restrict__ h_prev, float* __restrict__ out)
{
    int idx = blockIdx.x * 256 + threadIdx.x;   // 0..32767
    int i = idx >> 7, h4 = idx & 127;
    const float4* gir = (const float4*)(gi + (size_t)i * 1536);
    const float4* ghr = (const float4*)(gh + (size_t)i * 1536);
    float4 vir = gir[h4],       vhr = ghr[h4];
    float4 viz = gir[128 + h4], vhz = ghr[128 + h4];
    float4 vin = gir[256 + h4], vhn = ghr[256 + h4];
    float4 hp  = ((const float4*)(h_prev + (size_t)i * 512))[h4];
    float4 o;
    float* pir = &vir.x; float* phr = &vhr.x;
    float* piz = &viz.x; float* phz = &vhz.x;
    float* pin = &vin.x; float* phn = &vhn.x;
    float* php = &hp.x;  float* po = &o.x;
    #pragma unroll
    for (int j = 0; j < 4; ++j) {
        float r = sigm(pir[j] + phr[j]);
        float u = sigm(piz[j] + phz[j]);
        float c = tanhf(pin[j] + r * phn[j]);
        po[j] = (1.f - u) * c + u * php[j];
    }
    *(float4*)&out[O_HNEW + (size_t)i * 512 + h4 * 4] = o;
}

// ---------------- coop pass 1: S1[d], S2[d], C, SS via atomics (32 blocks) ----------------
__global__ __launch_bounds__(256) void coop_red_k(
    const float* __restrict__ out, float* __restrict__ red)
{
    int tid = threadIdx.x;
    int d = tid & 127, pair = tid >> 7;
    int b = blockIdx.x;                       // 0..31, agents b*8..b*8+7
    float s1 = 0.f, s2 = 0.f, c = 0.f, ss = 0.f;
    #pragma unroll
    for (int jj = 0; jj < 4; ++jj) {
        int i = b * 8 + jj * 2 + pair;
        float mu = out[O_MUQ + (size_t)i * 128 + d];
        float lv = out[O_LVQ + (size_t)i * 128 + d];
        float iv = expf(-lv);
        s1 += iv; s2 += mu * iv; c += mu * mu * iv; ss += lv;
    }
    atomicAdd(&red[d], s1);
    atomicAdd(&red[128 + d], s2);
    #pragma unroll
    for (int off = 32; off; off >>= 1) {
        c  += __shfl_down(c, off);
        ss += __shfl_down(ss, off);
    }
    if ((tid & 63) == 0) {
        atomicAdd(&red[256], c);
        atomicAdd(&red[257], ss);
    }
}

// ---------------- coop pass 2: per-agent coop -> cn (16 blocks, 16 lanes/agent) ----------------
__global__ __launch_bounds__(256) void coop_cn_k(
    const float* __restrict__ out, const float* __restrict__ red,
    const float* __restrict__ cw, const float* __restrict__ cb,
    float* __restrict__ cn)
{
    int tid = threadIdx.x;
    int a = (blockIdx.x << 4) + (tid >> 4);
    int s = tid & 15;
    const float* mur = out + O_MUQ + (size_t)a * 128 + s * 8;
    const float* lvr = out + O_LVQ + (size_t)a * 128 + s * 8;
    float acc1 = 0.f, acc2 = 0.f, slv = 0.f;
    #pragma unroll
    for (int j = 0; j < 8; ++j) {
        float mu = mur[j], lv = lvr[j];
        acc1 += (mu * mu + expf(lv)) * red[s * 8 + j];
        acc2 += mu * red[128 + s * 8 + j];
        slv  += lv;
    }
    #pragma unroll
    for (int m = 1; m < 16; m <<= 1) {
        acc1 += __shfl_xor(acc1, m);
        acc2 += __shfl_xor(acc2, m);
        slv  += __shfl_xor(slv, m);
    }
    if (s == 0) {
        float coop = 0.5f * (acc1 - 2.f * acc2 + red[256] + red[257]
                             - 256.f * slv - 32768.f) / 255.f;
        cn[a] = sigm(cw[0] * coop + cb[0]);
    }
}

// ---------------- GAT a/b vectors (16 blocks, 16 lanes/agent) ----------------
__global__ __launch_bounds__(256) void gat_ab_k(
    const float* __restrict__ Wh, const float* __restrict__ asrc,
    const float* __restrict__ adst, const float* __restrict__ cn,
    float* __restrict__ a, float* __restrict__ b)
{
    int tid = threadIdx.x;
    int i = (blockIdx.x << 4) + (tid >> 4);
    int s = tid & 15;
    const float4* wr = (const float4*)(Wh + (size_t)i * 256 + s * 16);
    const float4* s4 = (const float4*)(asrc + s * 16);
    const float4* d4 = (const float4*)(adst + s * 16);
    float sa = 0.f, sb = 0.f;
    #pragma unroll
    for (int q = 0; q < 4; ++q) {
        float4 w = wr[q], sv = s4[q], dv = d4[q];
        sa += w.x * sv.x + w.y * sv.y + w.z * sv.z + w.w * sv.w;
        sb += w.x * dv.x + w.y * dv.y + w.z * dv.z + w.w * dv.w;
    }
    #pragma unroll
    for (int m = 1; m < 16; m <<= 1) {
        sa += __shfl_xor(sa, m);
        sb += __shfl_xor(sb, m);
    }
    if (s == 0) {
        float c = cn[i];
        a[i] = sa + c;
        b[i] = sb + c;
    }
}

// ---------------- GAT softmax rows: alpha = softmax_j(lrelu(a_i + b_j)) ----------------
__global__ __launch_bounds__(256) void gat_softmax_k(
    const float* __restrict__ a, const float* __restrict__ b,
    float* __restrict__ alpha)
{
    __shared__ float bsh[256];
    __shared__ float ash[16];
    int tid = threadIdx.x;
    int b0 = blockIdx.x * 16;
    bsh[tid] = b[tid];
    if (tid < 16) ash[tid] = a[b0 + tid];
    __syncthreads();
    int li = tid >> 4, jg = tid & 15;
    float ai = ash[li];
    float e[16];
    float m = -1e30f;
    #pragma unroll
    for (int q = 0; q < 16; ++q) {
        float s = ai + bsh[jg * 16 + q];
        s = s > 0.f ? s : 0.2f * s;
        e[q] = s;
        m = fmaxf(m, s);
    }
    #pragma unroll
    for (int msk = 1; msk < 16; msk <<= 1) m = fmaxf(m, __shfl_xor(m, msk, 16));
    float sum = 0.f;
    #pragma unroll
    for (int q = 0; q < 16; ++q) { e[q] = expf(e[q] - m); sum += e[q]; }
    #pragma unroll
    for (int msk = 1; msk < 16; msk <<= 1) sum += __shfl_xor(sum, msk, 16);
    float inv = 1.f / sum;
    int i = b0 + li;
    float4* dst = (float4*)(alpha + (size_t)i * 256 + jg * 16);
    dst[0] = make_float4(e[0] * inv, e[1] * inv, e[2] * inv, e[3] * inv);
    dst[1] = make_float4(e[4] * inv, e[5] * inv, e[6] * inv, e[7] * inv);
    dst[2] = make_float4(e[8] * inv, e[9] * inv, e[10] * inv, e[11] * inv);
    dst[3] = make_float4(e[12] * inv, e[13] * inv, e[14] * inv, e[15] * inv);
}

// ---------------- per-agent head hidden layers: 8-row batches, max MLP ----------------
// grid = 4096: n(256) x sub(16). 4 waves/block, each wave owns 8 consecutive rows
// of the virtual 512-row [actor(256); critic(256)] weight block for agent n.
__global__ __launch_bounds__(256) void heads_hidden_k(
    const float* __restrict__ obs, const float* __restrict__ vgat,
    const float* __restrict__ Wa1, const float* __restrict__ ba1,
    const float* __restrict__ Wc1, const float* __restrict__ bc1,
    float* __restrict__ ha, float* __restrict__ hc)
{
    int bid = blockIdx.x;
    int n = bid >> 4, sub = bid & 15;
    int tid = threadIdx.x;
    int wave = tid >> 6, lane = tid & 63;
    // x[lane*8 .. +7]: lanes 0-31 obs, lanes 32-63 vgat
    float4 x0, x1;
    if (lane < 32) {
        const float4* s = (const float4*)(obs + (size_t)n * 256 + lane * 8);
        x0 = s[0]; x1 = s[1];
    } else {
        const float4* s = (const float4*)(vgat + (size_t)n * 256 + (lane - 32) * 8);
        x0 = s[0]; x1 = s[1];
    }
    int row0 = sub * 32 + wave * 8;          // 0..504, always 8-aligned, no a/c crossing
    int which = row0 >> 8;
    int r0 = row0 & 255;
    const float* Wb = (which ? Wc1 : Wa1) + (size_t)n * 131072 + (size_t)r0 * 512;
    const float* bb = (which ? bc1 : ba1) + (size_t)n * 256 + r0;
    float*       hb = (which ? hc : ha)  + (size_t)n * 256 + r0;
    // issue all 16 dwordx4 loads before any FMA -> 256 B/lane in flight
    float4 w[8][2];
    #pragma unroll
    for (int rr = 0; rr < 8; ++rr) {
        const float4* wr = (const float4*)(Wb + (size_t)rr * 512 + lane * 8);
        w[rr][0] = wr[0];
        w[rr][1] = wr[1];
    }
    float v[8];
    #pragma unroll
    for (int rr = 0; rr < 8; ++rr) {
        v[rr] = w[rr][0].x * x0.x + w[rr][0].y * x0.y + w[rr][0].z * x0.z + w[rr][0].w * x0.w
              + w[rr][1].x * x1.x + w[rr][1].y * x1.y + w[rr][1].z * x1.z + w[rr][1].w * x1.w;
    }
    #pragma unroll
    for (int off = 32; off; off >>= 1) {
        #pragma unroll
        for (int rr = 0; rr < 8; ++rr) v[rr] += __shfl_down(v[rr], off);
    }
    if (lane == 0) {
        #pragma unroll
        for (int rr = 0; rr < 8; ++rr)
            hb[rr] = fmaxf(v[rr] + bb[rr], 0.f);
    }
}

// ---------------- head output layers ----------------
__global__ __launch_bounds__(256) void heads_out_k(
    const float* __restrict__ ha, const float* __restrict__ hc,
    const float* __restrict__ Wa2, const float* __restrict__ ba2,
    const float* __restrict__ Wc2, const float* __restrict__ bc2,
    float* __restrict__ out)
{
    int n = blockIdx.x, tid = threadIdx.x;
    __shared__ __align__(16) float hA[256], hC[256];
    hA[tid] = ha[(size_t)n * 256 + tid];
    hC[tid] = hc[(size_t)n * 256 + tid];
    __syncthreads();
    int wave = tid >> 6, lane = tid & 63;
    const float4* h4 = (const float4*)hA;
    float4 hv = h4[lane];
    for (int o = wave; o < 16; o += 4) {
        const float4* w4 = (const float4*)(Wa2 + ((size_t)n * 16 + o) * 256);
        float4 wv = w4[lane];
        float v = wv.x * hv.x + wv.y * hv.y + wv.z * hv.z + wv.w * hv.w;
        #pragma unroll
        for (int off = 32; off; off >>= 1) v += __shfl_down(v, off);
        if (lane == 0) out[O_LOGITS + (size_t)n * 16 + o] = v + ba2[(size_t)n * 16 + o];
    }
    if (wave == 0) {
        const float4* w4 = (const float4*)(Wc2 + (size_t)n * 256);
        const float4* h4c = (const float4*)hC;
        float4 wv = w4[lane], hcv = h4c[lane];
        float v = wv.x * hcv.x + wv.y * hcv.y + wv.z * hcv.z + wv.w * hcv.w;
        #pragma unroll
        for (int off = 32; off; off >>= 1) v += __shfl_down(v, off);
        if (lane == 0) out[O_VALUES + n] = v + bc2[n];
    }
}

// ---------------- launch ----------------
extern "C" void kernel_launch(void* const* d_in, const int* in_sizes, int n_in,
                              void* d_out_v, int out_size, void* d_ws, size_t ws_size,
                              hipStream_t stream)
{
    const float* obs   = (const float*)d_in[0];
    const float* h_prev= (const float*)d_in[1];
    const float* eps   = (const float*)d_in[2];
    const float* Wp1 = (const float*)d_in[3];  const float* bp1 = (const float*)d_in[4];
    const float* Wp2 = (const float*)d_in[5];  const float* bp2 = (const float*)d_in[6];
    const float* We1 = (const float*)d_in[7];  const float* be1 = (const float*)d_in[8];
    const float* We2 = (const float*)d_in[9];  const float* be2 = (const float*)d_in[10];
    const float* Wd1 = (const float*)d_in[11]; const float* bd1 = (const float*)d_in[12];
    const float* Wd2 = (const float*)d_in[13]; const float* bd2 = (const float*)d_in[14];
    const float* Wih = (const float*)d_in[15]; const float* Whh = (const float*)d_in[16];
    const float* bih = (const float*)d_in[17]; const float* bhh = (const float*)d_in[18];
    const float* Wg1 = (const float*)d_in[19]; const float* as1 = (const float*)d_in[20];
    const float* ad1 = (const float*)d_in[21];
    const float* Wg2 = (const float*)d_in[22]; const float* as2 = (const float*)d_in[23];
    const float* ad2 = (const float*)d_in[24];
    const float* cw  = (const float*)d_in[25]; const float* cb  = (const float*)d_in[26];
    const float* Wa1 = (const float*)d_in[27]; const float* ba1 = (const float*)d_in[28];
    const float* Wa2 = (const float*)d_in[29]; const float* ba2 = (const float*)d_in[30];
    const float* Wc1 = (const float*)d_in[31]; const float* bc1 = (const float*)d_in[32];
    const float* Wc2 = (const float*)d_in[33]; const float* bc2 = (const float*)d_in[34];
    float* out = (float*)d_out_v;
    float* ws  = (float*)d_ws;
    dim3 blk(256);

    // zero reduction scratch (no deps)
    zero_k<<<dim3(1), dim3(320), 0, stream>>>(ws + W_RED);

    // S1: t1 = relu(h@Wp1+b), t2 = relu([obs,h]@We1+b), gh = h@Whh+bhh  (one launch)
    GDesc dt1 = {h_prev, nullptr, Wp1, bp1, ws + W_T1, 512, 0,   512, 1, 8};
    GDesc dt2 = {obs,    h_prev,  We1, be1, ws + W_T2, 256, 512, 512, 1, 8};
    GDesc dgh = {h_prev, nullptr, Whh, bhh, ws + W_GH, 512, 0,  1536, 0, 24};
    mgemm3<<<dim3(40, 4), blk, 0, stream>>>(dt1, dt2, dgh);

    // S2: pbuf = t1@Wp2+b, qbuf = t2@We2+b
    GDesc dp = {ws + W_T1, nullptr, Wp2, bp2, ws + W_PBUF, 512, 0, 256, 0, 4};
    GDesc dq = {ws + W_T2, nullptr, We2, be2, ws + W_QBUF, 512, 0, 256, 0, 4};
    mgemm2<<<dim3(8, 4), blk, 0, stream>>>(dp, dq);

    // mu_q / lv_q / z / kl
    post_pq<<<dim3(256), dim3(128), 0, stream>>>(ws + W_PBUF, ws + W_QBUF, eps, out);

    // coop reduction (depends only on mu_q/lv_q)
    coop_red_k<<<dim3(32), blk, 0, stream>>>(out, ws + W_RED);
    coop_cn_k<<<dim3(16), blk, 0, stream>>>(out, ws + W_RED, cw, cb, ws + W_CN);

    // S3: t3 = relu([z,h]@Wd1+b), gi = [obs,z]@Wih+bih
    GDesc dt3 = {out + O_Z, h_prev,    Wd1, bd1, ws + W_T3, 128, 512, 512, 1, 8};
    GDesc dgi = {obs,       out + O_Z, Wih, bih, ws + W_GI, 256, 128, 1536, 0, 24};
    mgemm2<<<dim3(32, 4), blk, 0, stream>>>(dt3, dgi);

    // S4: xbuf = t3@Wd2+b
    GDesc dx = {ws + W_T3, nullptr, Wd2, bd2, ws + W_XBUF, 512, 0, 512, 0, 8};
    mgemm1<<<dim3(8, 4), blk, 0, stream>>>(dx);
    nll_k<<<dim3(256), blk, 0, stream>>>(ws + W_XBUF, obs, out);

    // GRU -> h_new
    gru_k<<<dim3(128), blk, 0, stream>>>(ws + W_GI, ws + W_GH, h_prev, out);

    // GAT stage 1
    GDesc dw1 = {out + O_HNEW, nullptr, Wg1, nullptr, ws + W_WH1, 512, 0, 256, 0, 4};
    mgemm1<<<dim3(4, 4), blk, 0, stream>>>(dw1);
    gat_ab_k<<<dim3(16), blk, 0, stream>>>(ws + W_WH1, as1, ad1, ws + W_CN, ws + W_A1, ws + W_B1);
    gat_softmax_k<<<dim3(16), blk, 0, stream>>>(ws + W_A1, ws + W_B1, ws + W_ALPHA);
    gemm_nn<2><<<dim3(4, 4), blk, 0, stream>>>(ws + W_ALPHA, ws + W_WH1, ws + W_H1, 256, 256);

    // GAT stage 2
    GDesc dw2 = {ws + W_H1, nullptr, Wg2, nullptr, ws + W_WH2, 256, 0, 256, 0, 4};
    mgemm1<<<dim3(4, 4), blk, 0, stream>>>(dw2);
    gat_ab_k<<<dim3(16), blk, 0, stream>>>(ws + W_WH2, as2, ad2, ws + W_CN, ws + W_A2, ws + W_B2);
    gat_softmax_k<<<dim3(16), blk, 0, stream>>>(ws + W_A2, ws + W_B2, ws + W_ALPHA);
    gemm_nn<2><<<dim3(4, 4), blk, 0, stream>>>(ws + W_ALPHA, ws + W_WH2, out + O_VGAT, 256, 256);

    // per-agent actor/critic heads
    heads_hidden_k<<<dim3(4096), blk, 0, stream>>>(obs, out + O_VGAT, Wa1, ba1, Wc1, bc1,
                                                   ws + W_HA, ws + W_HC);
    heads_out_k<<<dim3(256), blk, 0, stream>>>(ws + W_HA, ws + W_HC, Wa2, ba2, Wc2, bc2, out);
}